// Round 3
// baseline (119.695 us; speedup 1.0000x reference)
//
#include <hip/hip_runtime.h>
#include <hip/hip_bf16.h>
#include <hip/hip_fp16.h>

// Self-attention: B=4, N=4096 (64x64 spatial), C=256, D=32.
// Pipeline:
//   proj_kernel : q,k,v = x@W{q,k,v}+b -> f16. q,k row-major [B*N][32]; v transposed [B][32][N].
//   attn_kernel : per block = 16 q-rows; 4 waves k-split flash attention with
//                 swapped-operand MFMA (S^T = K*Q^T, feat^T = V^T*P^T), then
//                 combine + output projection (feat@Wo+bo)*gamma + x.

#define BB 4
#define NN 4096
#define CC 256
#define DD 32

typedef _Float16 half_t;
typedef _Float16 half4_t __attribute__((ext_vector_type(4)));
typedef _Float16 half8_t __attribute__((ext_vector_type(8)));
typedef float f32x4 __attribute__((ext_vector_type(4)));

// PV matmul: v_mfma_f32_16x16x16_f16 (legacy-name builtin, no underscore before f16)
#define MFMA_PV(a, b, c) __builtin_amdgcn_mfma_f32_16x16x16f16(a, b, c, 0, 0, 0)

// ---------------- Kernel 1: fused QKV projection ----------------
// grid 256 blocks x 192 threads; block = 64 rows of x.
// thread: og = t%24 (4 consecutive out channels of the fused 96), rg = t/24 (8 rows).
__global__ __launch_bounds__(192) void proj_kernel(
    const float* __restrict__ x,
    const float* __restrict__ Wk, const float* __restrict__ bk,
    const float* __restrict__ Wq, const float* __restrict__ bq,
    const float* __restrict__ Wv, const float* __restrict__ bv,
    half_t* __restrict__ k_ws, half_t* __restrict__ q_ws, half_t* __restrict__ vT_ws)
{
    __shared__ float xs[64 * 264];  // stride 264 floats (16B-aligned rows, spreads banks)
    const int t = threadIdx.x;
    const int row0 = blockIdx.x * 64;

    // stage x tile [64][256] via float4
    const float4* x4 = reinterpret_cast<const float4*>(x) + row0 * 64;
    for (int idx = t; idx < 64 * 64; idx += 192) {
        int r = idx >> 6, c4 = idx & 63;
        float4 v = x4[r * 64 + c4];
        *reinterpret_cast<float4*>(&xs[r * 264 + c4 * 4]) = v;
    }
    __syncthreads();

    const int og = t % 24;       // 0..23 -> out channels og*4..og*4+3 of fused 96
    const int rg = t / 24;       // 0..7  -> rows rg*8..rg*8+7
    const int mat = og >> 3;     // 0:k 1:q 2:v
    const int ol = (og & 7) * 4; // 0..28 within the 32 outputs of one matrix
    const float* Wm = (mat == 0) ? Wk : ((mat == 1) ? Wq : Wv);
    const float* bm = (mat == 0) ? bk : ((mat == 1) ? bq : bv);

    float acc[4][8];
#pragma unroll
    for (int a = 0; a < 4; ++a)
#pragma unroll
        for (int r = 0; r < 8; ++r) acc[a][r] = 0.f;

    for (int c = 0; c < 256; ++c) {
        float4 w4 = *reinterpret_cast<const float4*>(Wm + c * DD + ol);
        const float* xr = &xs[rg * 8 * 264 + c];
#pragma unroll
        for (int rr = 0; rr < 8; ++rr) {
            float xv = xr[rr * 264];
            acc[0][rr] += xv * w4.x;
            acc[1][rr] += xv * w4.y;
            acc[2][rr] += xv * w4.z;
            acc[3][rr] += xv * w4.w;
        }
    }
    float b0 = bm[ol], b1 = bm[ol + 1], b2 = bm[ol + 2], b3 = bm[ol + 3];

    if (mat < 2) {
        half_t* dst = (mat == 0) ? k_ws : q_ws;
#pragma unroll
        for (int rr = 0; rr < 8; ++rr) {
            int row = row0 + rg * 8 + rr;
            half4_t h;
            h[0] = (half_t)(acc[0][rr] + b0);
            h[1] = (half_t)(acc[1][rr] + b1);
            h[2] = (half_t)(acc[2][rr] + b2);
            h[3] = (half_t)(acc[3][rr] + b3);
            *reinterpret_cast<half4_t*>(dst + row * DD + ol) = h;
        }
    } else {
        // v transposed: vT[b][d][n]
        const int b = row0 >> 12;               // row0 / 4096 (blocks never straddle batches)
        const int n0 = (row0 & (NN - 1)) + rg * 8;
        float bias[4] = {b0, b1, b2, b3};
#pragma unroll
        for (int oo = 0; oo < 4; ++oo) {
            int d = ol + oo;
            half8_t h;
#pragma unroll
            for (int rr = 0; rr < 8; ++rr) h[rr] = (half_t)(acc[oo][rr] + bias[oo]);
            *reinterpret_cast<half8_t*>(vT_ws + (size_t)(b * DD + d) * NN + n0) = h;
        }
    }
}

// ---------------- Kernel 2: flash attention + output projection ----------------
// grid 1024 blocks (b*256+qt) x 256 threads (4 waves). Block = 16 q rows.
// Wave w handles k in [w*1024, (w+1)*1024), tiles of 16.
__global__ __launch_bounds__(256) void attn_kernel(
    const half_t* __restrict__ k_ws, const half_t* __restrict__ q_ws,
    const half_t* __restrict__ vT_ws,
    const float* __restrict__ x, const float* __restrict__ Wo,
    const float* __restrict__ bo, const float* __restrict__ gamma,
    float* __restrict__ out)
{
    __shared__ float m_l[4][16];
    __shared__ float s_l[4][16];
    __shared__ float acc_l[4][64][8];
    __shared__ float feat_lds[16][32];

    const int tid = threadIdx.x;
    const int w = tid >> 6, lane = tid & 63;
    const int q = lane & 15, g = lane >> 4;        // q-row within tile / k-group
    const int b = blockIdx.x >> 8, qt = blockIdx.x & 255;
    const int qrow = b * NN + qt * 16 + q;

    // Q fragment: B-operand of S^T = K*Q^T.  Q[qrow][8g..8g+7]
    half8_t qf = *reinterpret_cast<const half8_t*>(q_ws + (size_t)qrow * DD + g * 8);

    float m = -3.0e38f, ssum = 0.f;
    f32x4 accd0 = {0.f, 0.f, 0.f, 0.f};   // feat^T, d = 4g+i
    f32x4 accd1 = {0.f, 0.f, 0.f, 0.f};   // feat^T, d = 16+4g+i

    const half_t* kbase = k_ws + ((size_t)b * NN + q) * DD + g * 8;
    const half_t* vbase = vT_ws + (size_t)b * DD * NN;

    const int kt0 = w * 64;
    for (int kt = kt0; kt < kt0 + 64; ++kt) {
        // K fragment: A-operand rows = k positions kt*16+q(lane&15)
        half8_t kf = *reinterpret_cast<const half8_t*>(kbase + (size_t)kt * 16 * DD);
        f32x4 s = __builtin_amdgcn_mfma_f32_16x16x32_f16(kf, qf, (f32x4){0.f, 0.f, 0.f, 0.f}, 0, 0, 0);
        // lane holds S[qbase+q][kt*16 + 4g + i]

        float tmax = fmaxf(fmaxf(s[0], s[1]), fmaxf(s[2], s[3]));
        tmax = fmaxf(tmax, __shfl_xor(tmax, 16));
        tmax = fmaxf(tmax, __shfl_xor(tmax, 32));
        float mn = fmaxf(m, tmax);
        float sc = __expf(m - mn);
        float p0 = __expf(s[0] - mn);
        float p1 = __expf(s[1] - mn);
        float p2 = __expf(s[2] - mn);
        float p3 = __expf(s[3] - mn);
        float psum = (p0 + p1) + (p2 + p3);
        psum += __shfl_xor(psum, 16);
        psum += __shfl_xor(psum, 32);
        ssum = ssum * sc + psum;
        m = mn;
        accd0 *= sc;
        accd1 *= sc;

        half4_t pf;  // P^T B-fragment: P[q][kt*16+4g+i] -- exactly the s-layout
        pf[0] = (half_t)p0; pf[1] = (half_t)p1; pf[2] = (half_t)p2; pf[3] = (half_t)p3;

        // V^T A-fragment: vT[dt*16 + q][kt*16 + 4g + i], contiguous half4 over i
        const half_t* vp = vbase + kt * 16 + g * 4;
        half4_t v0 = *reinterpret_cast<const half4_t*>(vp + (size_t)q * NN);
        half4_t v1 = *reinterpret_cast<const half4_t*>(vp + (size_t)(16 + q) * NN);
        accd0 = MFMA_PV(v0, pf, accd0);
        accd1 = MFMA_PV(v1, pf, accd1);
    }

    // publish per-wave partial state
    if (lane < 16) { m_l[w][lane] = m; s_l[w][lane] = ssum; }
#pragma unroll
    for (int i = 0; i < 4; ++i) {
        acc_l[w][lane][i] = accd0[i];
        acc_l[w][lane][4 + i] = accd1[i];
    }
    __syncthreads();

    // wave 0 combines the 4 k-splits
    if (w == 0) {
        float M = fmaxf(fmaxf(m_l[0][q], m_l[1][q]), fmaxf(m_l[2][q], m_l[3][q]));
        float SS = 0.f;
        float f[8] = {0.f, 0.f, 0.f, 0.f, 0.f, 0.f, 0.f, 0.f};
#pragma unroll
        for (int ww = 0; ww < 4; ++ww) {
            float sc = __expf(m_l[ww][q] - M);
            SS += s_l[ww][q] * sc;
#pragma unroll
            for (int i = 0; i < 8; ++i) f[i] += acc_l[ww][lane][i] * sc;
        }
        float inv = 1.0f / SS;
#pragma unroll
        for (int i = 0; i < 4; ++i) {
            feat_lds[q][g * 4 + i] = f[i] * inv;
            feat_lds[q][16 + g * 4 + i] = f[4 + i] * inv;
        }
    }
    __syncthreads();

    // epilogue: out[r][c] = gamma*(feat[r]@Wo[:,c] + bo[c]) + x[r][c], c = tid
    const int c = tid;
    float oacc[16];
#pragma unroll
    for (int r = 0; r < 16; ++r) oacc[r] = 0.f;
    for (int d = 0; d < DD; ++d) {
        float wv = Wo[d * CC + c];
#pragma unroll
        for (int r = 0; r < 16; ++r) oacc[r] += feat_lds[r][d] * wv;
    }
    const float gam = gamma[0];
    const float bias = bo[c];
    const size_t base = ((size_t)b * NN + (size_t)qt * 16) * CC + c;
    const float* xr = x + base;
    float* outr = out + base;
#pragma unroll
    for (int r = 0; r < 16; ++r)
        outr[(size_t)r * CC] = gam * (oacc[r] + bias) + xr[(size_t)r * CC];
}

// ---------------- launch ----------------
extern "C" void kernel_launch(void* const* d_in, const int* in_sizes, int n_in,
                              void* d_out, int out_size, void* d_ws, size_t ws_size,
                              hipStream_t stream) {
    const float* x  = (const float*)d_in[0];
    const float* Wk = (const float*)d_in[1];
    const float* bk = (const float*)d_in[2];
    const float* Wq = (const float*)d_in[3];
    const float* bq = (const float*)d_in[4];
    const float* Wv = (const float*)d_in[5];
    const float* bv = (const float*)d_in[6];
    const float* Wo = (const float*)d_in[7];
    const float* bo = (const float*)d_in[8];
    const float* gamma = (const float*)d_in[9];
    float* out = (float*)d_out;

    half_t* k_ws  = (half_t*)d_ws;
    half_t* q_ws  = k_ws + (size_t)BB * NN * DD;
    half_t* vT_ws = q_ws + (size_t)BB * NN * DD;

    proj_kernel<<<256, 192, 0, stream>>>(x, Wk, bk, Wq, bq, Wv, bv, k_ws, q_ws, vT_ws);
    attn_kernel<<<1024, 256, 0, stream>>>(k_ws, q_ws, vT_ws, x, Wo, bo, gamma, out);
}

// Round 4
// 111.291 us; speedup vs baseline: 1.0755x; 1.0755x over previous
//
#include <hip/hip_runtime.h>
#include <hip/hip_bf16.h>
#include <hip/hip_fp16.h>

// Self-attention: B=4, N=4096 (64x64 spatial), C=256, D=32.
//   proj_kernel : q,k,v = x@W{q,k,v}+b -> f16. q (pre-scaled by log2e), k row-major
//                 [B*N][32]; v transposed [B][32][N].
//   attn_kernel : block = 16 q-rows, 8 waves k-split (512 k each) flash attention,
//                 swapped-operand MFMA (S^T = K*Q^T, feat^T = V^T*P^T),
//                 4 k-tiles per iteration, defer-max (THR in log2 domain),
//                 lane-local ssum (no in-loop shuffles), then combine + output proj.

#define BB 4
#define NN 4096
#define CC 256
#define DD 32
#define LOG2E 1.44269504088896340736f
#define THR2 11.0f

typedef _Float16 half_t;
typedef _Float16 half4_t __attribute__((ext_vector_type(4)));
typedef _Float16 half8_t __attribute__((ext_vector_type(8)));
typedef float f32x4 __attribute__((ext_vector_type(4)));

#define MFMA_QK(a, b, c) __builtin_amdgcn_mfma_f32_16x16x32_f16(a, b, c, 0, 0, 0)
#define MFMA_PV(a, b, c) __builtin_amdgcn_mfma_f32_16x16x16f16(a, b, c, 0, 0, 0)

static __device__ inline float fexp2(float x) {
#if __has_builtin(__builtin_amdgcn_exp2f)
    return __builtin_amdgcn_exp2f(x);
#else
    return exp2f(x);
#endif
}

// ---------------- Kernel 1: fused QKV projection ----------------
// grid 1024 blocks x 192 threads; block = 16 rows of x.
// thread: og = t%24 (4 consecutive out channels of fused 96), rg = t/24 (2 rows).
__global__ __launch_bounds__(192) void proj_kernel(
    const float* __restrict__ x,
    const float* __restrict__ Wk, const float* __restrict__ bk,
    const float* __restrict__ Wq, const float* __restrict__ bq,
    const float* __restrict__ Wv, const float* __restrict__ bv,
    half_t* __restrict__ k_ws, half_t* __restrict__ q_ws, half_t* __restrict__ vT_ws)
{
    __shared__ float xs[16 * 264];
    const int t = threadIdx.x;
    const int row0 = blockIdx.x * 16;

    const float4* x4 = reinterpret_cast<const float4*>(x) + (size_t)row0 * 64;
    for (int idx = t; idx < 16 * 64; idx += 192) {
        int r = idx >> 6, c4 = idx & 63;
        *reinterpret_cast<float4*>(&xs[r * 264 + c4 * 4]) = x4[r * 64 + c4];
    }
    __syncthreads();

    const int og = t % 24;        // 4 channels of fused 96
    const int rg = t / 24;        // 0..7 -> rows rg*2, rg*2+1
    const int mat = og >> 3;      // 0:k 1:q 2:v
    const int ol = (og & 7) * 4;
    const float* Wm = (mat == 0) ? Wk : ((mat == 1) ? Wq : Wv);
    const float* bm = (mat == 0) ? bk : ((mat == 1) ? bq : bv);

    float a00 = 0.f, a01 = 0.f, a10 = 0.f, a11 = 0.f,
          a20 = 0.f, a21 = 0.f, a30 = 0.f, a31 = 0.f;
    const float* xr = &xs[rg * 2 * 264];
    for (int c = 0; c < 256; ++c) {
        float4 w4 = *reinterpret_cast<const float4*>(Wm + c * DD + ol);
        float x0 = xr[c], x1 = xr[264 + c];
        a00 += x0 * w4.x; a01 += x1 * w4.x;
        a10 += x0 * w4.y; a11 += x1 * w4.y;
        a20 += x0 * w4.z; a21 += x1 * w4.z;
        a30 += x0 * w4.w; a31 += x1 * w4.w;
    }
    float b0 = bm[ol], b1 = bm[ol + 1], b2 = bm[ol + 2], b3 = bm[ol + 3];
    const float scl = (mat == 1) ? LOG2E : 1.0f;  // q pre-scaled: softmax in log2 domain

    if (mat < 2) {
        half_t* dst = (mat == 0) ? k_ws : q_ws;
        int row = row0 + rg * 2;
        half4_t h0, h1;
        h0[0] = (half_t)((a00 + b0) * scl); h1[0] = (half_t)((a01 + b0) * scl);
        h0[1] = (half_t)((a10 + b1) * scl); h1[1] = (half_t)((a11 + b1) * scl);
        h0[2] = (half_t)((a20 + b2) * scl); h1[2] = (half_t)((a21 + b2) * scl);
        h0[3] = (half_t)((a30 + b3) * scl); h1[3] = (half_t)((a31 + b3) * scl);
        *reinterpret_cast<half4_t*>(dst + (size_t)row * DD + ol) = h0;
        *reinterpret_cast<half4_t*>(dst + (size_t)(row + 1) * DD + ol) = h1;
    } else {
        // vT[b][d][n], half2 per (d, row-pair)
        typedef _Float16 half2_t __attribute__((ext_vector_type(2)));
        const int b = row0 >> 12;
        const int n0 = (row0 & (NN - 1)) + rg * 2;
        float ar[4][2] = {{a00, a01}, {a10, a11}, {a20, a21}, {a30, a31}};
        float bb[4] = {b0, b1, b2, b3};
#pragma unroll
        for (int oo = 0; oo < 4; ++oo) {
            half2_t h;
            h[0] = (half_t)(ar[oo][0] + bb[oo]);
            h[1] = (half_t)(ar[oo][1] + bb[oo]);
            *reinterpret_cast<half2_t*>(vT_ws + (size_t)(b * DD + ol + oo) * NN + n0) = h;
        }
    }
}

// ---------------- Kernel 2: flash attention + output projection ----------------
// grid 1024 blocks (b*256+qt) x 512 threads (8 waves). Block = 16 q rows.
// Wave w: k in [w*512, (w+1)*512), 4 tiles of 16 per iteration.
__global__ __launch_bounds__(512) void attn_kernel(
    const half_t* __restrict__ k_ws, const half_t* __restrict__ q_ws,
    const half_t* __restrict__ vT_ws,
    const float* __restrict__ x, const float* __restrict__ Wo,
    const float* __restrict__ bo, const float* __restrict__ gamma,
    float* __restrict__ out)
{
    __shared__ float m_l[8][16];
    __shared__ float s_l[8][16];
    __shared__ float acc_l[8][64][8];
    __shared__ float feat_lds[16][32];

    const int tid = threadIdx.x;
    const int w = tid >> 6, lane = tid & 63;
    const int q = lane & 15, g = lane >> 4;
    const int b = blockIdx.x >> 8, qt = blockIdx.x & 255;
    const int qrow = b * NN + qt * 16 + q;

    // Q fragment (B-operand of S^T = K*Q^T): Q[qrow][8g..8g+7], pre-scaled by log2e
    half8_t qf = *reinterpret_cast<const half8_t*>(q_ws + (size_t)qrow * DD + g * 8);

    float m = -3.0e38f, ssum = 0.f;
    f32x4 accd0 = {0.f, 0.f, 0.f, 0.f};   // feat^T, d = 4g+i
    f32x4 accd1 = {0.f, 0.f, 0.f, 0.f};   // feat^T, d = 16+4g+i

    const half_t* kbase = k_ws + ((size_t)b * NN + q) * DD + g * 8;
    const half_t* vbase = vT_ws + (size_t)b * DD * NN + g * 4;

    for (int it = 0; it < 8; ++it) {
        const int kt = w * 32 + it * 4;
        // 4 independent QK^T MFMAs (64 k positions)
        half8_t kf0 = *reinterpret_cast<const half8_t*>(kbase + (size_t)(kt + 0) * 16 * DD);
        half8_t kf1 = *reinterpret_cast<const half8_t*>(kbase + (size_t)(kt + 1) * 16 * DD);
        half8_t kf2 = *reinterpret_cast<const half8_t*>(kbase + (size_t)(kt + 2) * 16 * DD);
        half8_t kf3 = *reinterpret_cast<const half8_t*>(kbase + (size_t)(kt + 3) * 16 * DD);
        f32x4 z = {0.f, 0.f, 0.f, 0.f};
        f32x4 s0 = MFMA_QK(kf0, qf, z);
        f32x4 s1 = MFMA_QK(kf1, qf, z);
        f32x4 s2 = MFMA_QK(kf2, qf, z);
        f32x4 s3 = MFMA_QK(kf3, qf, z);

        // lane-local max of 16 s-values (log2 domain)
        float tA = fmaxf(fmaxf(s0[0], s0[1]), fmaxf(s0[2], s0[3]));
        float tB = fmaxf(fmaxf(s1[0], s1[1]), fmaxf(s1[2], s1[3]));
        float tC = fmaxf(fmaxf(s2[0], s2[1]), fmaxf(s2[2], s2[3]));
        float tD = fmaxf(fmaxf(s3[0], s3[1]), fmaxf(s3[2], s3[3]));
        float tmax = fmaxf(fmaxf(tA, tB), fmaxf(tC, tD));

        // defer-max: rescale only when some lane exceeds headroom
        if (!__all(tmax <= m + THR2)) {
            float rmax = tmax;
            rmax = fmaxf(rmax, __shfl_xor(rmax, 16));
            rmax = fmaxf(rmax, __shfl_xor(rmax, 32));
            float mn = fmaxf(m, rmax);
            float sc = fexp2(m - mn);
            ssum *= sc;
            accd0 *= sc;
            accd1 *= sc;
            m = mn;
        }

        // V^T fragments (A-operand): vT[d][k], d = {q, 16+q}, k = kt*16+g*4+j
        const half_t* vp0 = vbase + (size_t)q * NN + kt * 16;
        const half_t* vp1 = vbase + (size_t)(16 + q) * NN + kt * 16;

        // tile 0
        {
            float p0 = fexp2(s0[0] - m), p1 = fexp2(s0[1] - m);
            float p2 = fexp2(s0[2] - m), p3 = fexp2(s0[3] - m);
            ssum += (p0 + p1) + (p2 + p3);
            half4_t pf; pf[0] = (half_t)p0; pf[1] = (half_t)p1; pf[2] = (half_t)p2; pf[3] = (half_t)p3;
            half4_t v0 = *reinterpret_cast<const half4_t*>(vp0);
            half4_t v1 = *reinterpret_cast<const half4_t*>(vp1);
            accd0 = MFMA_PV(v0, pf, accd0);
            accd1 = MFMA_PV(v1, pf, accd1);
        }
        // tile 1
        {
            float p0 = fexp2(s1[0] - m), p1 = fexp2(s1[1] - m);
            float p2 = fexp2(s1[2] - m), p3 = fexp2(s1[3] - m);
            ssum += (p0 + p1) + (p2 + p3);
            half4_t pf; pf[0] = (half_t)p0; pf[1] = (half_t)p1; pf[2] = (half_t)p2; pf[3] = (half_t)p3;
            half4_t v0 = *reinterpret_cast<const half4_t*>(vp0 + 16);
            half4_t v1 = *reinterpret_cast<const half4_t*>(vp1 + 16);
            accd0 = MFMA_PV(v0, pf, accd0);
            accd1 = MFMA_PV(v1, pf, accd1);
        }
        // tile 2
        {
            float p0 = fexp2(s2[0] - m), p1 = fexp2(s2[1] - m);
            float p2 = fexp2(s2[2] - m), p3 = fexp2(s2[3] - m);
            ssum += (p0 + p1) + (p2 + p3);
            half4_t pf; pf[0] = (half_t)p0; pf[1] = (half_t)p1; pf[2] = (half_t)p2; pf[3] = (half_t)p3;
            half4_t v0 = *reinterpret_cast<const half4_t*>(vp0 + 32);
            half4_t v1 = *reinterpret_cast<const half4_t*>(vp1 + 32);
            accd0 = MFMA_PV(v0, pf, accd0);
            accd1 = MFMA_PV(v1, pf, accd1);
        }
        // tile 3
        {
            float p0 = fexp2(s3[0] - m), p1 = fexp2(s3[1] - m);
            float p2 = fexp2(s3[2] - m), p3 = fexp2(s3[3] - m);
            ssum += (p0 + p1) + (p2 + p3);
            half4_t pf; pf[0] = (half_t)p0; pf[1] = (half_t)p1; pf[2] = (half_t)p2; pf[3] = (half_t)p3;
            half4_t v0 = *reinterpret_cast<const half4_t*>(vp0 + 48);
            half4_t v1 = *reinterpret_cast<const half4_t*>(vp1 + 48);
            accd0 = MFMA_PV(v0, pf, accd0);
            accd1 = MFMA_PV(v1, pf, accd1);
        }
    }

    // fold lane-local ssum to row sum (once)
    ssum += __shfl_xor(ssum, 16);
    ssum += __shfl_xor(ssum, 32);

    if (lane < 16) { m_l[w][lane] = m; s_l[w][lane] = ssum; }
#pragma unroll
    for (int i = 0; i < 4; ++i) {
        acc_l[w][lane][i] = accd0[i];
        acc_l[w][lane][4 + i] = accd1[i];
    }
    __syncthreads();

    // wave 0 combines the 8 k-splits
    if (w == 0) {
        float M = m_l[0][q];
#pragma unroll
        for (int ww = 1; ww < 8; ++ww) M = fmaxf(M, m_l[ww][q]);
        float SS = 0.f;
        float f[8] = {0.f, 0.f, 0.f, 0.f, 0.f, 0.f, 0.f, 0.f};
#pragma unroll
        for (int ww = 0; ww < 8; ++ww) {
            float sc = fexp2(m_l[ww][q] - M);
            SS += s_l[ww][q] * sc;
#pragma unroll
            for (int i = 0; i < 8; ++i) f[i] += acc_l[ww][lane][i] * sc;
        }
        float inv = 1.0f / SS;
#pragma unroll
        for (int i = 0; i < 4; ++i) {
            feat_lds[q][g * 4 + i] = f[i] * inv;
            feat_lds[q][16 + g * 4 + i] = f[4 + i] * inv;
        }
    }
    __syncthreads();

    // epilogue: 512 threads; c = tid&255, rh = tid>>8 -> 8 rows each
    const int c = tid & 255, rh = tid >> 8;
    float oacc[8];
#pragma unroll
    for (int r = 0; r < 8; ++r) oacc[r] = 0.f;
    for (int d = 0; d < DD; ++d) {
        float wv = Wo[d * CC + c];
#pragma unroll
        for (int r = 0; r < 8; ++r) oacc[r] += feat_lds[rh * 8 + r][d] * wv;
    }
    const float gam = gamma[0];
    const float bias = bo[c];
    const size_t base = ((size_t)b * NN + (size_t)qt * 16 + rh * 8) * CC + c;
    const float* xr = x + base;
    float* outr = out + base;
#pragma unroll
    for (int r = 0; r < 8; ++r)
        outr[(size_t)r * CC] = gam * (oacc[r] + bias) + xr[(size_t)r * CC];
}

// ---------------- launch ----------------
extern "C" void kernel_launch(void* const* d_in, const int* in_sizes, int n_in,
                              void* d_out, int out_size, void* d_ws, size_t ws_size,
                              hipStream_t stream) {
    const float* x  = (const float*)d_in[0];
    const float* Wk = (const float*)d_in[1];
    const float* bk = (const float*)d_in[2];
    const float* Wq = (const float*)d_in[3];
    const float* bq = (const float*)d_in[4];
    const float* Wv = (const float*)d_in[5];
    const float* bv = (const float*)d_in[6];
    const float* Wo = (const float*)d_in[7];
    const float* bo = (const float*)d_in[8];
    const float* gamma = (const float*)d_in[9];
    float* out = (float*)d_out;

    half_t* k_ws  = (half_t*)d_ws;
    half_t* q_ws  = k_ws + (size_t)BB * NN * DD;
    half_t* vT_ws = q_ws + (size_t)BB * NN * DD;

    proj_kernel<<<1024, 192, 0, stream>>>(x, Wk, bk, Wq, bq, Wv, bv, k_ws, q_ws, vT_ws);
    attn_kernel<<<1024, 512, 0, stream>>>(k_ws, q_ws, vT_ws, x, Wo, bo, gamma, out);
}